// Round 3
// baseline (1170.997 us; speedup 1.0000x reference)
//
#include <hip/hip_runtime.h>

// SpMM: out[i,d] = sum_{e: rows[e]==i} vals[e] * x[cols[e], d]
// N=100000, E=1600000, DIM=32, fp32.
//
// Round 3: row-granular scatter wrote 64B/edge (write-allocate on random
// lines -> 100MB). Now bin edges into buckets of 128 rows (782 buckets):
//  - scatter destinations are bucket-dense -> lines fill fully (~13MB writes)
//  - phase 2: block per bucket, 16KB LDS accumulator, ds_add_f32 (no global
//    atomics), coalesced float4 writeout (covers all rows, no out memset).

#define N_NODES 100000
#define N_EDGES 1600000
#define DIM 32

#define BUCKET_ROWS 128
#define BUCKET_SHIFT 7
#define NBUCK ((N_NODES + BUCKET_ROWS - 1) / BUCKET_ROWS)   // 782
#define LDS_FLOATS (BUCKET_ROWS * DIM)                      // 4096 = 16KB

// ---- workspace layout (in ints) ----
#define WS_SCV    0                       // int2 per edge: [0, 3200000)
#define WS_COUNTS 3200000                 // 782 (padded 784)
#define WS_BPTR   3200784                 // 783
#define WS_CURSOR 3201568                 // 782
#define WS_TOTAL_INTS 3202352             // ~12.81 MB

__global__ __launch_bounds__(256) void bhist_kernel(
    const int* __restrict__ rows, int* __restrict__ counts)
{
    int e = blockIdx.x * 256 + threadIdx.x;
    if (e < N_EDGES) atomicAdd(&counts[rows[e] >> BUCKET_SHIFT], 1);
}

__global__ __launch_bounds__(1024) void bscan_kernel(
    const int* __restrict__ counts, int* __restrict__ bptr,
    int* __restrict__ cursor)
{
    __shared__ int lds[1024];
    int t = threadIdx.x;
    int v = (t < NBUCK) ? counts[t] : 0;
    lds[t] = v;
    __syncthreads();
    for (int off = 1; off < 1024; off <<= 1) {
        int tv = (t >= off) ? lds[t - off] : 0;
        __syncthreads();
        lds[t] += tv;
        __syncthreads();
    }
    int excl = lds[t] - v;
    if (t < NBUCK) { bptr[t] = excl; cursor[t] = excl; }
    if (t == 0) bptr[NBUCK] = N_EDGES;
}

__global__ __launch_bounds__(256) void bscatter_kernel(
    const int* __restrict__ rows, const int* __restrict__ cols,
    const float* __restrict__ vals, int* __restrict__ cursor,
    int2* __restrict__ scv)
{
    int e = blockIdx.x * 256 + threadIdx.x;
    if (e < N_EDGES) {
        int r = rows[e];
        int p = atomicAdd(&cursor[r >> BUCKET_SHIFT], 1);
        int packed = ((r & (BUCKET_ROWS - 1)) << 17) | cols[e];
        scv[p] = make_int2(packed, __float_as_int(vals[e]));
    }
}

// one block per bucket; 32 lanes per edge (8 edges in flight per block)
__global__ __launch_bounds__(256) void bucket_gather_kernel(
    const int* __restrict__ bptr, const int2* __restrict__ scv,
    const float* __restrict__ x, float4* __restrict__ out4)
{
    __shared__ float acc[LDS_FLOATS];
    const int b = blockIdx.x;
    for (int i = threadIdx.x; i < LDS_FLOATS; i += 256) acc[i] = 0.f;
    __syncthreads();

    const int beg = bptr[b];
    const int end = bptr[b + 1];
    const int d = threadIdx.x & 31;   // dim lane
    const int g = threadIdx.x >> 5;   // edge slot 0..7
    for (int e = beg + g; e < end; e += 8) {
        int2 cv = scv[e];
        int col = cv.x & 0x1FFFF;
        int rl  = ((unsigned)cv.x) >> 17;
        float v = __int_as_float(cv.y);
        float xv = x[col * DIM + d];
        atomicAdd(&acc[rl * DIM + d], v * xv);   // ds_add_f32
    }
    __syncthreads();

    const int r0 = b * BUCKET_ROWS;
    const int rows = min(BUCKET_ROWS, N_NODES - r0);
    const int nf4 = rows * (DIM / 4);
    const float4* a4 = (const float4*)acc;
    for (int i = threadIdx.x; i < nf4; i += 256)
        out4[r0 * (DIM / 4) + i] = a4[i];
}

// ---- fallback (round-1 path) if ws too small ----
__global__ __launch_bounds__(256) void spmm_atomic_kernel(
    const int* __restrict__ rows, const int* __restrict__ cols,
    const float* __restrict__ vals, const float* __restrict__ x,
    float* __restrict__ out)
{
    long long idx = (long long)blockIdx.x * blockDim.x + threadIdx.x;
    if (idx >= (long long)N_EDGES * DIM) return;
    int e = (int)(idx >> 5);
    int d = (int)(idx & 31);
    atomicAdd(&out[(long long)rows[e] * DIM + d], vals[e] * x[(long long)cols[e] * DIM + d]);
}

extern "C" void kernel_launch(void* const* d_in, const int* in_sizes, int n_in,
                              void* d_out, int out_size, void* d_ws, size_t ws_size,
                              hipStream_t stream) {
    const int*   A_rows = (const int*)d_in[0];
    const int*   A_cols = (const int*)d_in[1];
    const float* A_vals = (const float*)d_in[2];
    const float* x      = (const float*)d_in[3];
    float*       out    = (float*)d_out;

    if (ws_size < (size_t)WS_TOTAL_INTS * sizeof(int)) {
        hipMemsetAsync(out, 0, (size_t)out_size * sizeof(float), stream);
        long long total = (long long)N_EDGES * DIM;
        spmm_atomic_kernel<<<(unsigned)((total + 255) / 256), 256, 0, stream>>>(
            A_rows, A_cols, A_vals, x, out);
        return;
    }

    int*  ws     = (int*)d_ws;
    int2* scv    = (int2*)(ws + WS_SCV);
    int*  counts = ws + WS_COUNTS;
    int*  bptr   = ws + WS_BPTR;
    int*  cursor = ws + WS_CURSOR;

    hipMemsetAsync(counts, 0, NBUCK * sizeof(int), stream);

    bhist_kernel<<<(N_EDGES + 255) / 256, 256, 0, stream>>>(A_rows, counts);
    bscan_kernel<<<1, 1024, 0, stream>>>(counts, bptr, cursor);
    bscatter_kernel<<<(N_EDGES + 255) / 256, 256, 0, stream>>>(
        A_rows, A_cols, A_vals, cursor, scv);
    bucket_gather_kernel<<<NBUCK, 256, 0, stream>>>(
        bptr, scv, x, (float4*)out);
}

// Round 4
// 495.106 us; speedup vs baseline: 2.3651x; 2.3651x over previous
//
#include <hip/hip_runtime.h>

// SpMM: out[i,d] = sum_{e: rows[e]==i} vals[e] * x[cols[e], d]
// N=100000, E=1600000, DIM=32, fp32.
//
// Round 4: per-block binning (radix-sort style).
//  - hist: per-block LDS histogram over 782 buckets -> count matrix m[b][blk]
//    (no contended global atomics)
//  - scan: 3-kernel exclusive scan of m in (bucket, block) order
//  - scatter: block loads its cursor column into LDS, LDS-atomic slot claim,
//    each (block,bucket) run written by ONE block -> lines merge in its L2
//  - gather: block per bucket, 16KB LDS accumulator, ds_add_f32, float4 out

#define N_NODES 100000
#define N_EDGES 1600000
#define DIM 32

#define BUCKET_ROWS 128
#define BUCKET_SHIFT 7
#define NBUCK ((N_NODES + BUCKET_ROWS - 1) / BUCKET_ROWS)   // 782
#define LDS_FLOATS (BUCKET_ROWS * DIM)                      // 4096 = 16KB

#define TILE 16384
#define NBLK ((N_EDGES + TILE - 1) / TILE)                  // 98
#define MATN (NBUCK * NBLK)                                 // 76636
#define SCANB 1024
#define NSCAN ((MATN + SCANB - 1) / SCANB)                  // 75

// ---- workspace layout (in ints) ----
#define WS_SCV   0                        // int2 per edge: [0, 3200000)
#define WS_MAT   3200000                  // 76636 (pad 76672)
#define WS_BSUM  3276672                  // 128
#define WS_TOTAL_INTS 3276800             // ~13.1 MB

// 1) per-block LDS histogram -> m[b*NBLK + blk]
__global__ __launch_bounds__(256) void hist_kernel(
    const int* __restrict__ rows, int* __restrict__ mat)
{
    __shared__ int h[NBUCK];
    for (int i = threadIdx.x; i < NBUCK; i += 256) h[i] = 0;
    __syncthreads();
    const int base = blockIdx.x * TILE;
    for (int i = 0; i < TILE / 256; ++i) {
        int e = base + threadIdx.x + i * 256;
        if (e < N_EDGES) atomicAdd(&h[rows[e] >> BUCKET_SHIFT], 1);
    }
    __syncthreads();
    for (int b = threadIdx.x; b < NBUCK; b += 256)
        mat[b * NBLK + blockIdx.x] = h[b];
}

// 2a) block-wise exclusive scan of mat (1024/block), emit block sums
__global__ __launch_bounds__(SCANB) void scanA_kernel(
    int* __restrict__ mat, int* __restrict__ bsum)
{
    __shared__ int lds[SCANB];
    int i = blockIdx.x * SCANB + threadIdx.x;
    int v = (i < MATN) ? mat[i] : 0;
    lds[threadIdx.x] = v;
    __syncthreads();
    for (int off = 1; off < SCANB; off <<= 1) {
        int t = (threadIdx.x >= off) ? lds[threadIdx.x - off] : 0;
        __syncthreads();
        lds[threadIdx.x] += t;
        __syncthreads();
    }
    int incl = lds[threadIdx.x];
    if (i < MATN) mat[i] = incl - v;
    if (threadIdx.x == SCANB - 1) bsum[blockIdx.x] = incl;
}

// 2b) scan the 75 block sums
__global__ __launch_bounds__(128) void scanB_kernel(int* __restrict__ bsum)
{
    __shared__ int lds[128];
    int v = (threadIdx.x < NSCAN) ? bsum[threadIdx.x] : 0;
    lds[threadIdx.x] = v;
    __syncthreads();
    for (int off = 1; off < 128; off <<= 1) {
        int t = (threadIdx.x >= off) ? lds[threadIdx.x - off] : 0;
        __syncthreads();
        lds[threadIdx.x] += t;
        __syncthreads();
    }
    if (threadIdx.x < NSCAN) bsum[threadIdx.x] = lds[threadIdx.x] - v;
}

// 2c) add block offsets
__global__ __launch_bounds__(SCANB) void scanC_kernel(
    int* __restrict__ mat, const int* __restrict__ bsum)
{
    int i = blockIdx.x * SCANB + threadIdx.x;
    if (i < MATN) mat[i] += bsum[blockIdx.x];
}

// 3) scatter: per-block LDS cursors = scanned column; runs owned by one block
__global__ __launch_bounds__(256) void scatter_kernel(
    const int* __restrict__ rows, const int* __restrict__ cols,
    const float* __restrict__ vals, const int* __restrict__ mat,
    int2* __restrict__ scv)
{
    __shared__ int cur[NBUCK];
    for (int b = threadIdx.x; b < NBUCK; b += 256)
        cur[b] = mat[b * NBLK + blockIdx.x];
    __syncthreads();
    const int base = blockIdx.x * TILE;
    for (int i = 0; i < TILE / 256; ++i) {
        int e = base + threadIdx.x + i * 256;
        if (e < N_EDGES) {
            int r = rows[e];
            int p = atomicAdd(&cur[r >> BUCKET_SHIFT], 1);
            int packed = ((r & (BUCKET_ROWS - 1)) << 17) | cols[e];
            scv[p] = make_int2(packed, __float_as_int(vals[e]));
        }
    }
}

// 4) gather: block per bucket, LDS accumulator, ds_add_f32, float4 writeout
__global__ __launch_bounds__(256) void gather_kernel(
    const int* __restrict__ mat, const int2* __restrict__ scv,
    const float* __restrict__ x, float4* __restrict__ out4)
{
    __shared__ float acc[LDS_FLOATS];
    const int b = blockIdx.x;
    for (int i = threadIdx.x; i < LDS_FLOATS; i += 256) acc[i] = 0.f;
    __syncthreads();

    const int beg = mat[b * NBLK];
    const int end = (b + 1 < NBUCK) ? mat[(b + 1) * NBLK] : N_EDGES;
    const int d = threadIdx.x & 31;   // dim lane
    const int g = threadIdx.x >> 5;   // edge slot 0..7
    for (int e = beg + g; e < end; e += 8) {
        int2 cv = scv[e];
        int col = cv.x & 0x1FFFF;
        int rl  = ((unsigned)cv.x) >> 17;
        float v = __int_as_float(cv.y);
        float xv = x[col * DIM + d];
        atomicAdd(&acc[rl * DIM + d], v * xv);   // ds_add_f32, conflict-free
    }
    __syncthreads();

    const int r0 = b * BUCKET_ROWS;
    const int nrows = min(BUCKET_ROWS, N_NODES - r0);
    const int nf4 = nrows * (DIM / 4);
    const float4* a4 = (const float4*)acc;
    for (int i = threadIdx.x; i < nf4; i += 256)
        out4[r0 * (DIM / 4) + i] = a4[i];
}

// ---- fallback (round-1 path) if ws too small ----
__global__ __launch_bounds__(256) void spmm_atomic_kernel(
    const int* __restrict__ rows, const int* __restrict__ cols,
    const float* __restrict__ vals, const float* __restrict__ x,
    float* __restrict__ out)
{
    long long idx = (long long)blockIdx.x * blockDim.x + threadIdx.x;
    if (idx >= (long long)N_EDGES * DIM) return;
    int e = (int)(idx >> 5);
    int d = (int)(idx & 31);
    atomicAdd(&out[(long long)rows[e] * DIM + d], vals[e] * x[(long long)cols[e] * DIM + d]);
}

extern "C" void kernel_launch(void* const* d_in, const int* in_sizes, int n_in,
                              void* d_out, int out_size, void* d_ws, size_t ws_size,
                              hipStream_t stream) {
    const int*   A_rows = (const int*)d_in[0];
    const int*   A_cols = (const int*)d_in[1];
    const float* A_vals = (const float*)d_in[2];
    const float* x      = (const float*)d_in[3];
    float*       out    = (float*)d_out;

    if (ws_size < (size_t)WS_TOTAL_INTS * sizeof(int)) {
        hipMemsetAsync(out, 0, (size_t)out_size * sizeof(float), stream);
        long long total = (long long)N_EDGES * DIM;
        spmm_atomic_kernel<<<(unsigned)((total + 255) / 256), 256, 0, stream>>>(
            A_rows, A_cols, A_vals, x, out);
        return;
    }

    int*  ws   = (int*)d_ws;
    int2* scv  = (int2*)(ws + WS_SCV);
    int*  mat  = ws + WS_MAT;
    int*  bsum = ws + WS_BSUM;

    hist_kernel <<<NBLK, 256, 0, stream>>>(A_rows, mat);
    scanA_kernel<<<NSCAN, SCANB, 0, stream>>>(mat, bsum);
    scanB_kernel<<<1, 128, 0, stream>>>(bsum);
    scanC_kernel<<<NSCAN, SCANB, 0, stream>>>(mat, bsum);
    scatter_kernel<<<NBLK, 256, 0, stream>>>(A_rows, A_cols, A_vals, mat, scv);
    gather_kernel<<<NBUCK, 256, 0, stream>>>(mat, scv, x, (float4*)out);
}

// Round 5
// 421.727 us; speedup vs baseline: 2.7767x; 1.1740x over previous
//
#include <hip/hip_runtime.h>

// SpMM: out[i,d] = sum_{e: rows[e]==i} vals[e] * x[cols[e], d]
// N=100000, E=1600000, DIM=32, fp32.
//
// Round 5: gather was latency-bound (occ 22.6%, VALUBusy 3.4%, 270GB/s).
//  - BUCKET_ROWS 64 -> 1563 gather blocks (~6/CU), LDS acc 8KB
//  - gather edge loop unrolled x4: 4 independent scv+x load chains in
//    flight per 32-lane edge slot (4x MLP)
//  - hist/scatter TILE 8192 -> 196 blocks

#define N_NODES 100000
#define N_EDGES 1600000
#define DIM 32

#define BUCKET_ROWS 64
#define BUCKET_SHIFT 6
#define NBUCK ((N_NODES + BUCKET_ROWS - 1) / BUCKET_ROWS)   // 1563
#define LDS_FLOATS (BUCKET_ROWS * DIM)                      // 2048 = 8KB

#define TILE 8192
#define NBLK ((N_EDGES + TILE - 1) / TILE)                  // 196
#define MATN (NBUCK * NBLK)                                 // 306348
#define SCANB 1024
#define NSCAN ((MATN + SCANB - 1) / SCANB)                  // 300

// ---- workspace layout (in ints) ----
#define WS_SCV   0                        // int2 per edge: [0, 3200000)
#define WS_MAT   3200000                  // 306348 (pad 306432)
#define WS_BSUM  3506432                  // 512
#define WS_TOTAL_INTS 3506944             // ~14.03 MB

// 1) per-block LDS histogram -> mat[b*NBLK + blk]
__global__ __launch_bounds__(256) void hist_kernel(
    const int* __restrict__ rows, int* __restrict__ mat)
{
    __shared__ int h[NBUCK];
    for (int i = threadIdx.x; i < NBUCK; i += 256) h[i] = 0;
    __syncthreads();
    const int base = blockIdx.x * TILE;
    for (int i = 0; i < TILE / 256; ++i) {
        int e = base + threadIdx.x + i * 256;
        if (e < N_EDGES) atomicAdd(&h[rows[e] >> BUCKET_SHIFT], 1);
    }
    __syncthreads();
    for (int b = threadIdx.x; b < NBUCK; b += 256)
        mat[b * NBLK + blockIdx.x] = h[b];
}

// 2a) block-wise exclusive scan of mat, emit block sums
__global__ __launch_bounds__(SCANB) void scanA_kernel(
    int* __restrict__ mat, int* __restrict__ bsum)
{
    __shared__ int lds[SCANB];
    int i = blockIdx.x * SCANB + threadIdx.x;
    int v = (i < MATN) ? mat[i] : 0;
    lds[threadIdx.x] = v;
    __syncthreads();
    for (int off = 1; off < SCANB; off <<= 1) {
        int t = (threadIdx.x >= off) ? lds[threadIdx.x - off] : 0;
        __syncthreads();
        lds[threadIdx.x] += t;
        __syncthreads();
    }
    int incl = lds[threadIdx.x];
    if (i < MATN) mat[i] = incl - v;
    if (threadIdx.x == SCANB - 1) bsum[blockIdx.x] = incl;
}

// 2b) scan the 300 block sums
__global__ __launch_bounds__(512) void scanB_kernel(int* __restrict__ bsum)
{
    __shared__ int lds[512];
    int v = (threadIdx.x < NSCAN) ? bsum[threadIdx.x] : 0;
    lds[threadIdx.x] = v;
    __syncthreads();
    for (int off = 1; off < 512; off <<= 1) {
        int t = (threadIdx.x >= off) ? lds[threadIdx.x - off] : 0;
        __syncthreads();
        lds[threadIdx.x] += t;
        __syncthreads();
    }
    if (threadIdx.x < NSCAN) bsum[threadIdx.x] = lds[threadIdx.x] - v;
}

// 2c) add block offsets
__global__ __launch_bounds__(SCANB) void scanC_kernel(
    int* __restrict__ mat, const int* __restrict__ bsum)
{
    int i = blockIdx.x * SCANB + threadIdx.x;
    if (i < MATN) mat[i] += bsum[blockIdx.x];
}

// 3) scatter: per-block LDS cursors; each (bucket,block) run owned by 1 block
__global__ __launch_bounds__(256) void scatter_kernel(
    const int* __restrict__ rows, const int* __restrict__ cols,
    const float* __restrict__ vals, const int* __restrict__ mat,
    int2* __restrict__ scv)
{
    __shared__ int cur[NBUCK];
    for (int b = threadIdx.x; b < NBUCK; b += 256)
        cur[b] = mat[b * NBLK + blockIdx.x];
    __syncthreads();
    const int base = blockIdx.x * TILE;
    for (int i = 0; i < TILE / 256; ++i) {
        int e = base + threadIdx.x + i * 256;
        if (e < N_EDGES) {
            int r = rows[e];
            int p = atomicAdd(&cur[r >> BUCKET_SHIFT], 1);
            int packed = ((r & (BUCKET_ROWS - 1)) << 17) | cols[e];
            scv[p] = make_int2(packed, __float_as_int(vals[e]));
        }
    }
}

// 4) gather: block per bucket, LDS accumulator, x4-unrolled MLP
__global__ __launch_bounds__(256) void gather_kernel(
    const int* __restrict__ mat, const int2* __restrict__ scv,
    const float* __restrict__ x, float4* __restrict__ out4)
{
    __shared__ float acc[LDS_FLOATS];
    const int b = blockIdx.x;
    for (int i = threadIdx.x; i < LDS_FLOATS; i += 256) acc[i] = 0.f;
    __syncthreads();

    const int beg = mat[b * NBLK];
    const int end = (b + 1 < NBUCK) ? mat[(b + 1) * NBLK] : N_EDGES;
    const int d = threadIdx.x & 31;   // dim lane
    const int g = threadIdx.x >> 5;   // edge slot 0..7

    int e = beg + g;
    // 4-deep unroll: 4 independent load chains in flight per slot
    for (; e + 24 < end; e += 32) {
        int2 cv0 = scv[e];
        int2 cv1 = scv[e + 8];
        int2 cv2 = scv[e + 16];
        int2 cv3 = scv[e + 24];
        float xv0 = x[(cv0.x & 0x1FFFF) * DIM + d];
        float xv1 = x[(cv1.x & 0x1FFFF) * DIM + d];
        float xv2 = x[(cv2.x & 0x1FFFF) * DIM + d];
        float xv3 = x[(cv3.x & 0x1FFFF) * DIM + d];
        atomicAdd(&acc[(((unsigned)cv0.x) >> 17) * DIM + d], __int_as_float(cv0.y) * xv0);
        atomicAdd(&acc[(((unsigned)cv1.x) >> 17) * DIM + d], __int_as_float(cv1.y) * xv1);
        atomicAdd(&acc[(((unsigned)cv2.x) >> 17) * DIM + d], __int_as_float(cv2.y) * xv2);
        atomicAdd(&acc[(((unsigned)cv3.x) >> 17) * DIM + d], __int_as_float(cv3.y) * xv3);
    }
    for (; e < end; e += 8) {
        int2 cv = scv[e];
        float xv = x[(cv.x & 0x1FFFF) * DIM + d];
        atomicAdd(&acc[(((unsigned)cv.x) >> 17) * DIM + d], __int_as_float(cv.y) * xv);
    }
    __syncthreads();

    const int r0 = b * BUCKET_ROWS;
    const int nrows = min(BUCKET_ROWS, N_NODES - r0);
    const int nf4 = nrows * (DIM / 4);
    const float4* a4 = (const float4*)acc;
    for (int i = threadIdx.x; i < nf4; i += 256)
        out4[r0 * (DIM / 4) + i] = a4[i];
}

// ---- fallback (round-1 path) if ws too small ----
__global__ __launch_bounds__(256) void spmm_atomic_kernel(
    const int* __restrict__ rows, const int* __restrict__ cols,
    const float* __restrict__ vals, const float* __restrict__ x,
    float* __restrict__ out)
{
    long long idx = (long long)blockIdx.x * blockDim.x + threadIdx.x;
    if (idx >= (long long)N_EDGES * DIM) return;
    int e = (int)(idx >> 5);
    int d = (int)(idx & 31);
    atomicAdd(&out[(long long)rows[e] * DIM + d], vals[e] * x[(long long)cols[e] * DIM + d]);
}

extern "C" void kernel_launch(void* const* d_in, const int* in_sizes, int n_in,
                              void* d_out, int out_size, void* d_ws, size_t ws_size,
                              hipStream_t stream) {
    const int*   A_rows = (const int*)d_in[0];
    const int*   A_cols = (const int*)d_in[1];
    const float* A_vals = (const float*)d_in[2];
    const float* x      = (const float*)d_in[3];
    float*       out    = (float*)d_out;

    if (ws_size < (size_t)WS_TOTAL_INTS * sizeof(int)) {
        hipMemsetAsync(out, 0, (size_t)out_size * sizeof(float), stream);
        long long total = (long long)N_EDGES * DIM;
        spmm_atomic_kernel<<<(unsigned)((total + 255) / 256), 256, 0, stream>>>(
            A_rows, A_cols, A_vals, x, out);
        return;
    }

    int*  ws   = (int*)d_ws;
    int2* scv  = (int2*)(ws + WS_SCV);
    int*  mat  = ws + WS_MAT;
    int*  bsum = ws + WS_BSUM;

    hist_kernel <<<NBLK, 256, 0, stream>>>(A_rows, mat);
    scanA_kernel<<<NSCAN, SCANB, 0, stream>>>(mat, bsum);
    scanB_kernel<<<1, 512, 0, stream>>>(bsum);
    scanC_kernel<<<NSCAN, SCANB, 0, stream>>>(mat, bsum);
    scatter_kernel<<<NBLK, 256, 0, stream>>>(A_rows, A_cols, A_vals, mat, scv);
    gather_kernel<<<NBUCK, 256, 0, stream>>>(mat, scv, x, (float4*)out);
}